// Round 10
// baseline (586.348 us; speedup 1.0000x reference)
//
#include <hip/hip_runtime.h>
#include <math.h>

#define BB 64
#define SS 2048
#define DD 512
#define SC 32                 // rows per chunk in K2
#define NC (SS / SC)          // 64 chunks per batch row

// ---------------------------------------------------------------------------
// K1: query[b,d] = sum_k hidden2[b,k] * W[d,k] + bias[d]
// grid (D/4, B), block 256 = 4 waves; wave w computes output d = bx*4 + w.
// ---------------------------------------------------------------------------
__global__ void query_kernel(const float* __restrict__ hidden2,
                             const float* __restrict__ W,
                             const float* __restrict__ bias,
                             float* __restrict__ q) {
    const int b    = blockIdx.y;
    const int wave = threadIdx.x >> 6;
    const int lane = threadIdx.x & 63;
    const int d    = blockIdx.x * 4 + wave;

    const float4* h4 = reinterpret_cast<const float4*>(hidden2 + (size_t)b * DD);
    const float4* w4 = reinterpret_cast<const float4*>(W + (size_t)d * DD);
    float4 a0 = h4[lane];
    float4 a1 = h4[64 + lane];
    float4 b0 = w4[lane];
    float4 b1 = w4[64 + lane];
    float p = a0.x*b0.x + a0.y*b0.y + a0.z*b0.z + a0.w*b0.w
            + a1.x*b1.x + a1.y*b1.y + a1.z*b1.z + a1.w*b1.w;
    #pragma unroll
    for (int off = 32; off; off >>= 1) p += __shfl_xor(p, off, 64);
    if (lane == 0) q[b * DD + d] = p + bias[d];
}

// ---------------------------------------------------------------------------
// K2: per (chunk, b): E for all SC=32 rows (static bounds), single-wave chunk
// softmax with nv-masking, PV partial with static 16-iter loop.
// block 256 = 4 waves; grid (NC, B) = 4096 blocks (~2048 active).
// ---------------------------------------------------------------------------
__global__ void chunk_kernel(const float* __restrict__ key,
                             const float* __restrict__ value,
                             const float* __restrict__ q,
                             const int* __restrict__ seq_lens,
                             float* __restrict__ attn,     // [B,S] unnormalized out
                             float* __restrict__ mc,       // [B,NC]
                             float* __restrict__ lc,       // [B,NC]
                             float* __restrict__ ctxp) {   // [B,NC,D]
    const int b     = blockIdx.y;
    const int chunk = blockIdx.x;
    const int len   = seq_lens[b];
    const int s0    = chunk * SC;
    if (s0 >= len) return;
    const int nv = min(SC, len - s0);      // valid rows in this chunk

    const int t    = threadIdx.x;
    const int wave = t >> 6;
    const int lane = t & 63;

    __shared__ float  E_lds[SC];
    __shared__ float  p_lds[SC];
    __shared__ float4 cred[128];

    // ---- phase 1: E[r] = key[b,s0+r,:] . q[b,:]  for ALL 32 rows ----
    const float4* q4 = reinterpret_cast<const float4*>(q + (size_t)b * DD);
    const float4 q0 = q4[lane];
    const float4 q1 = q4[64 + lane];

    const float4* kbase =
        reinterpret_cast<const float4*>(key + ((size_t)b * SS + s0) * DD);

    float part[8];
    #pragma unroll
    for (int i = 0; i < 8; ++i) {
        const int r = wave + 4 * i;
        const float4 k0 = kbase[(size_t)r * (DD / 4) + lane];
        const float4 k1 = kbase[(size_t)r * (DD / 4) + 64 + lane];
        part[i] = k0.x*q0.x + k0.y*q0.y + k0.z*q0.z + k0.w*q0.w
                + k1.x*q1.x + k1.y*q1.y + k1.z*q1.z + k1.w*q1.w;
    }
    #pragma unroll
    for (int i = 0; i < 8; ++i) {
        float p = part[i];
        #pragma unroll
        for (int off = 32; off; off >>= 1) p += __shfl_xor(p, off, 64);
        if (lane == 0) E_lds[wave + 4 * i] = p;
    }
    __syncthreads();

    // ---- phase 2: chunk softmax on wave 0; p_lds fully written (0 if r>=nv)
    if (wave == 0) {
        const float e = (lane < nv) ? E_lds[lane] : -INFINITY;
        float m = e;
        #pragma unroll
        for (int off = 32; off; off >>= 1) m = fmaxf(m, __shfl_xor(m, off, 64));
        const float p = (lane < nv) ? __expf(e - m) : 0.f;
        if (lane < SC) p_lds[lane] = p;
        if (lane < nv) attn[(size_t)b * SS + s0 + lane] = p;
        float l = p;
        #pragma unroll
        for (int off = 32; off; off >>= 1) l += __shfl_xor(l, off, 64);
        if (lane == 0) { mc[b * NC + chunk] = m; lc[b * NC + chunk] = l; }
    }
    __syncthreads();

    // ---- phase 3: PV partial, static 16-iter loop ----
    const int d4   = t & 127;          // float4 index: d = 4*d4
    const int half = t >> 7;
    const float4* vbase =
        reinterpret_cast<const float4*>(value + ((size_t)b * SS + s0) * DD) + d4;

    float4 acc = make_float4(0.f, 0.f, 0.f, 0.f);
    #pragma unroll
    for (int i = 0; i < 16; ++i) {
        const int r = half + 2 * i;
        const float4 v = vbase[(size_t)r * (DD / 4)];
        const float p = p_lds[r];      // broadcast read; 0 for invalid rows
        acc.x += p * v.x; acc.y += p * v.y; acc.z += p * v.z; acc.w += p * v.w;
    }
    __syncthreads();
    if (half) cred[d4] = acc;
    __syncthreads();
    if (!half) {
        const float4 o = cred[d4];
        acc.x += o.x; acc.y += o.y; acc.z += o.z; acc.w += o.w;
        *reinterpret_cast<float4*>(ctxp + ((size_t)b * NC + chunk) * DD + 4 * d4) = acc;
    }
}

// ---------------------------------------------------------------------------
// K3: per b: global (m,l) from chunk partials; ctx = sum_c ctxp*scale / l;
// attn *= exp(m_c-m)/l in place; zero masked tail. grid B, block 256.
// c-loop is now a STATIC 64-iteration loop (sc_[c]=0 masks invalid chunks;
// poison ctxp values are finite so 0*x == -0, safe) -> batched parallel loads.
// ---------------------------------------------------------------------------
__global__ void combine_kernel(const float* __restrict__ mc,
                               const float* __restrict__ lc,
                               const float* __restrict__ ctxp,
                               const int* __restrict__ seq_lens,
                               float* __restrict__ attn,
                               float* __restrict__ ctx) {
    const int b   = blockIdx.x;
    const int t   = threadIdx.x;
    const int len = seq_lens[b];
    const int ncb = (len + SC - 1) / SC;   // active chunks

    __shared__ float sm;                   // global l (for ctx)
    __shared__ float sa[NC];               // exp(m_c - m) / l  per chunk
    __shared__ float sc_[NC];              // exp(m_c - m)      per chunk

    // wave 0: lane = chunk index (NC == 64 == wave width)
    if (t < 64) {
        const float m_c = (t < ncb) ? mc[b * NC + t] : -INFINITY;
        const float l_c = (t < ncb) ? lc[b * NC + t] : 0.f;
        float m = m_c;
        #pragma unroll
        for (int off = 32; off; off >>= 1) m = fmaxf(m, __shfl_xor(m, off, 64));
        float l = l_c * ((t < ncb) ? __expf(m_c - m) : 0.f);
        #pragma unroll
        for (int off = 32; off; off >>= 1) l += __shfl_xor(l, off, 64);
        const float e = (t < ncb) ? __expf(m_c - m) : 0.f;
        sc_[t] = e;
        sa[t]  = e / l;
        if (t == 0) sm = l;
    }
    __syncthreads();
    const float inv_l = 1.0f / sm;

    // context: threads 0..127 each own 4 d's; static 64-iter unrolled loop
    if (t < 128) {
        float4 acc = make_float4(0.f, 0.f, 0.f, 0.f);
        #pragma unroll
        for (int c = 0; c < NC; ++c) {
            const float4 v = *reinterpret_cast<const float4*>(
                ctxp + ((size_t)b * NC + c) * DD + 4 * t);
            const float s = sc_[c];    // 0 for c >= ncb
            acc.x += s * v.x; acc.y += s * v.y; acc.z += s * v.z; acc.w += s * v.w;
        }
        acc.x *= inv_l; acc.y *= inv_l; acc.z *= inv_l; acc.w *= inv_l;
        *reinterpret_cast<float4*>(ctx + (size_t)b * DD + 4 * t) = acc;
    }

    // attn rescale + masked tail
    float* a = attn + (size_t)b * SS;
    for (int s = t; s < SS; s += 256) {
        if (s < len) a[s] *= sa[s >> 5];   // s>>5 == s/SC
        else         a[s]  = 0.f;
    }
}

// ---------------------------------------------------------------------------
extern "C" void kernel_launch(void* const* d_in, const int* in_sizes, int n_in,
                              void* d_out, int out_size, void* d_ws, size_t ws_size,
                              hipStream_t stream) {
    const float* hidden2  = (const float*)d_in[0];
    const float* key      = (const float*)d_in[1];
    const float* value    = (const float*)d_in[2];
    const int*   seq_lens = (const int*)  d_in[3];
    const float* W        = (const float*)d_in[4];
    const float* bias     = (const float*)d_in[5];

    float* out  = (float*)d_out;
    float* ctx  = out;               // [B, D]
    float* attn = out + BB * DD;     // [B, S]

    float* ws    = (float*)d_ws;
    float* q     = ws;                                  // [B, D]
    float* mc    = ws + BB * DD;                        // [B, NC]
    float* lc    = mc + BB * NC;                        // [B, NC]
    float* ctxp  = lc + BB * NC;                        // [B, NC, D]
    // --- instrumentation scratch (dup chunk runs; never read back) ---
    float* attn2 = ctxp  + (size_t)BB * NC * DD;        // [B, S]
    float* mc2   = attn2 + (size_t)BB * SS;             // [B, NC]
    float* lc2   = mc2   + BB * NC;                     // [B, NC]
    float* ctxp2 = lc2   + BB * NC;                     // [B, NC, D]

    query_kernel  <<<dim3(DD / 4, BB), 256, 0, stream>>>(hidden2, W, bias, q);
    chunk_kernel  <<<dim3(NC, BB),     256, 0, stream>>>(key, value, q, seq_lens,
                                                         attn, mc, lc, ctxp);
    // INSTRUMENTATION: two duplicate chunk runs into scratch. dur delta / 2
    // = standalone chunk_kernel duration (268 MB working set > 256 MB L3,
    // so dups run effectively cold like the real one).
    chunk_kernel  <<<dim3(NC, BB),     256, 0, stream>>>(key, value, q, seq_lens,
                                                         attn2, mc2, lc2, ctxp2);
    chunk_kernel  <<<dim3(NC, BB),     256, 0, stream>>>(key, value, q, seq_lens,
                                                         attn2, mc2, lc2, ctxp2);
    combine_kernel<<<BB,               256, 0, stream>>>(mc, lc, ctxp, seq_lens,
                                                         attn, ctx);
}

// Round 11
// 487.073 us; speedup vs baseline: 1.2038x; 1.2038x over previous
//
#include <hip/hip_runtime.h>
#include <math.h>

#define BB 64
#define SS 2048
#define DD 512
#define SC 32                 // rows per chunk in K2
#define NC (SS / SC)          // 64 chunks per batch row

// ---------------------------------------------------------------------------
// K1: query[b,d] = sum_k hidden2[b,k] * W[d,k] + bias[d]
// grid (D/4, B), block 256 = 4 waves; wave w computes output d = bx*4 + w.
// ---------------------------------------------------------------------------
__global__ void query_kernel(const float* __restrict__ hidden2,
                             const float* __restrict__ W,
                             const float* __restrict__ bias,
                             float* __restrict__ q) {
    const int b    = blockIdx.y;
    const int wave = threadIdx.x >> 6;
    const int lane = threadIdx.x & 63;
    const int d    = blockIdx.x * 4 + wave;

    const float4* h4 = reinterpret_cast<const float4*>(hidden2 + (size_t)b * DD);
    const float4* w4 = reinterpret_cast<const float4*>(W + (size_t)d * DD);
    float4 a0 = h4[lane];
    float4 a1 = h4[64 + lane];
    float4 b0 = w4[lane];
    float4 b1 = w4[64 + lane];
    float p = a0.x*b0.x + a0.y*b0.y + a0.z*b0.z + a0.w*b0.w
            + a1.x*b1.x + a1.y*b1.y + a1.z*b1.z + a1.w*b1.w;
    #pragma unroll
    for (int off = 32; off; off >>= 1) p += __shfl_xor(p, off, 64);
    if (lane == 0) q[b * DD + d] = p + bias[d];
}

// ---------------------------------------------------------------------------
// K2: per (chunk, b): E for all SC=32 rows (static bounds), single-wave chunk
// softmax with nv-masking, PV partial with static 16-iter loop.
// block 256 = 4 waves; grid (NC, B) = 4096 blocks (~2048 active).
// Measured standalone (R10 dup-launch instrumentation): ~49 µs at ~5.7 TB/s
// effective read throughput (~90% of achievable HBM ceiling) -> memory-bound.
// ---------------------------------------------------------------------------
__global__ void chunk_kernel(const float* __restrict__ key,
                             const float* __restrict__ value,
                             const float* __restrict__ q,
                             const int* __restrict__ seq_lens,
                             float* __restrict__ attn,     // [B,S] unnormalized out
                             float* __restrict__ mc,       // [B,NC]
                             float* __restrict__ lc,       // [B,NC]
                             float* __restrict__ ctxp) {   // [B,NC,D]
    const int b     = blockIdx.y;
    const int chunk = blockIdx.x;
    const int len   = seq_lens[b];
    const int s0    = chunk * SC;
    if (s0 >= len) return;
    const int nv = min(SC, len - s0);      // valid rows in this chunk

    const int t    = threadIdx.x;
    const int wave = t >> 6;
    const int lane = t & 63;

    __shared__ float  E_lds[SC];
    __shared__ float  p_lds[SC];
    __shared__ float4 cred[128];

    // ---- phase 1: E[r] = key[b,s0+r,:] . q[b,:]  for ALL 32 rows ----
    const float4* q4 = reinterpret_cast<const float4*>(q + (size_t)b * DD);
    const float4 q0 = q4[lane];
    const float4 q1 = q4[64 + lane];

    const float4* kbase =
        reinterpret_cast<const float4*>(key + ((size_t)b * SS + s0) * DD);

    float part[8];
    #pragma unroll
    for (int i = 0; i < 8; ++i) {
        const int r = wave + 4 * i;
        const float4 k0 = kbase[(size_t)r * (DD / 4) + lane];
        const float4 k1 = kbase[(size_t)r * (DD / 4) + 64 + lane];
        part[i] = k0.x*q0.x + k0.y*q0.y + k0.z*q0.z + k0.w*q0.w
                + k1.x*q1.x + k1.y*q1.y + k1.z*q1.z + k1.w*q1.w;
    }
    #pragma unroll
    for (int i = 0; i < 8; ++i) {
        float p = part[i];
        #pragma unroll
        for (int off = 32; off; off >>= 1) p += __shfl_xor(p, off, 64);
        if (lane == 0) E_lds[wave + 4 * i] = p;
    }
    __syncthreads();

    // ---- phase 2: chunk softmax on wave 0; p_lds fully written (0 if r>=nv)
    if (wave == 0) {
        const float e = (lane < nv) ? E_lds[lane] : -INFINITY;
        float m = e;
        #pragma unroll
        for (int off = 32; off; off >>= 1) m = fmaxf(m, __shfl_xor(m, off, 64));
        const float p = (lane < nv) ? __expf(e - m) : 0.f;
        if (lane < SC) p_lds[lane] = p;
        if (lane < nv) attn[(size_t)b * SS + s0 + lane] = p;
        float l = p;
        #pragma unroll
        for (int off = 32; off; off >>= 1) l += __shfl_xor(l, off, 64);
        if (lane == 0) { mc[b * NC + chunk] = m; lc[b * NC + chunk] = l; }
    }
    __syncthreads();

    // ---- phase 3: PV partial, static 16-iter loop ----
    const int d4   = t & 127;          // float4 index: d = 4*d4
    const int half = t >> 7;
    const float4* vbase =
        reinterpret_cast<const float4*>(value + ((size_t)b * SS + s0) * DD) + d4;

    float4 acc = make_float4(0.f, 0.f, 0.f, 0.f);
    #pragma unroll
    for (int i = 0; i < 16; ++i) {
        const int r = half + 2 * i;
        const float4 v = vbase[(size_t)r * (DD / 4)];
        const float p = p_lds[r];      // broadcast read; 0 for invalid rows
        acc.x += p * v.x; acc.y += p * v.y; acc.z += p * v.z; acc.w += p * v.w;
    }
    __syncthreads();
    if (half) cred[d4] = acc;
    __syncthreads();
    if (!half) {
        const float4 o = cred[d4];
        acc.x += o.x; acc.y += o.y; acc.z += o.z; acc.w += o.w;
        *reinterpret_cast<float4*>(ctxp + ((size_t)b * NC + chunk) * DD + 4 * d4) = acc;
    }
}

// ---------------------------------------------------------------------------
// K3: per b: global (m,l) from chunk partials; ctx = sum_c ctxp*scale / l;
// attn *= exp(m_c-m)/l in place; zero masked tail. grid B, block 256.
// Static 64-iter c-loop (sc_[c]=0 masks invalid chunks; poison ctxp is
// finite so 0*x == -0, safe) -> batched parallel loads.
// ---------------------------------------------------------------------------
__global__ void combine_kernel(const float* __restrict__ mc,
                               const float* __restrict__ lc,
                               const float* __restrict__ ctxp,
                               const int* __restrict__ seq_lens,
                               float* __restrict__ attn,
                               float* __restrict__ ctx) {
    const int b   = blockIdx.x;
    const int t   = threadIdx.x;
    const int len = seq_lens[b];
    const int ncb = (len + SC - 1) / SC;   // active chunks

    __shared__ float sm;                   // global l (for ctx)
    __shared__ float sa[NC];               // exp(m_c - m) / l  per chunk
    __shared__ float sc_[NC];              // exp(m_c - m)      per chunk

    // wave 0: lane = chunk index (NC == 64 == wave width)
    if (t < 64) {
        const float m_c = (t < ncb) ? mc[b * NC + t] : -INFINITY;
        const float l_c = (t < ncb) ? lc[b * NC + t] : 0.f;
        float m = m_c;
        #pragma unroll
        for (int off = 32; off; off >>= 1) m = fmaxf(m, __shfl_xor(m, off, 64));
        float l = l_c * ((t < ncb) ? __expf(m_c - m) : 0.f);
        #pragma unroll
        for (int off = 32; off; off >>= 1) l += __shfl_xor(l, off, 64);
        const float e = (t < ncb) ? __expf(m_c - m) : 0.f;
        sc_[t] = e;
        sa[t]  = e / l;
        if (t == 0) sm = l;
    }
    __syncthreads();
    const float inv_l = 1.0f / sm;

    // context: threads 0..127 each own 4 d's; static 64-iter unrolled loop
    if (t < 128) {
        float4 acc = make_float4(0.f, 0.f, 0.f, 0.f);
        #pragma unroll
        for (int c = 0; c < NC; ++c) {
            const float4 v = *reinterpret_cast<const float4*>(
                ctxp + ((size_t)b * NC + c) * DD + 4 * t);
            const float s = sc_[c];    // 0 for c >= ncb
            acc.x += s * v.x; acc.y += s * v.y; acc.z += s * v.z; acc.w += s * v.w;
        }
        acc.x *= inv_l; acc.y *= inv_l; acc.z *= inv_l; acc.w *= inv_l;
        *reinterpret_cast<float4*>(ctx + (size_t)b * DD + 4 * t) = acc;
    }

    // attn rescale + masked tail
    float* a = attn + (size_t)b * SS;
    for (int s = t; s < SS; s += 256) {
        if (s < len) a[s] *= sa[s >> 5];   // s>>5 == s/SC
        else         a[s]  = 0.f;
    }
}

// ---------------------------------------------------------------------------
extern "C" void kernel_launch(void* const* d_in, const int* in_sizes, int n_in,
                              void* d_out, int out_size, void* d_ws, size_t ws_size,
                              hipStream_t stream) {
    const float* hidden2  = (const float*)d_in[0];
    const float* key      = (const float*)d_in[1];
    const float* value    = (const float*)d_in[2];
    const int*   seq_lens = (const int*)  d_in[3];
    const float* W        = (const float*)d_in[4];
    const float* bias     = (const float*)d_in[5];

    float* out  = (float*)d_out;
    float* ctx  = out;               // [B, D]
    float* attn = out + BB * DD;     // [B, S]

    float* ws   = (float*)d_ws;
    float* q    = ws;                         // [B, D]
    float* mc   = ws + BB * DD;               // [B, NC]
    float* lc   = mc + BB * NC;               // [B, NC]
    float* ctxp = lc + BB * NC;               // [B, NC, D]

    query_kernel  <<<dim3(DD / 4, BB), 256, 0, stream>>>(hidden2, W, bias, q);
    chunk_kernel  <<<dim3(NC, BB),     256, 0, stream>>>(key, value, q, seq_lens,
                                                         attn, mc, lc, ctxp);
    combine_kernel<<<BB,               256, 0, stream>>>(mc, lc, ctxp, seq_lens,
                                                         attn, ctx);
}